// Round 2
// baseline (163.715 us; speedup 1.0000x reference)
//
#include <hip/hip_runtime.h>
#include <hip/hip_bf16.h>

#define N_NODES 4096
#define IN_F    512
#define HEADS   8
#define DH      64
#define HD      512   // HEADS*DH

typedef __bf16 bf16x8 __attribute__((ext_vector_type(8)));
typedef float  f32x4  __attribute__((ext_vector_type(4)));

// ---------------- Kernel 0: prep
//   Wt[c][f] = bf16(W[h][f][d])  (c = h*64+d)   -- B^T operand for the GEMM
//   v[h][f]  = sum_d W[h][f][d] * a_dst[h][d]   -- fp32, for exact logits
__global__ __launch_bounds__(64) void k0_prep(const float* __restrict__ W,
                                              const float* __restrict__ a_dst,
                                              __bf16* __restrict__ Wt,
                                              float* __restrict__ v) {
    int b = blockIdx.x;
    int lane = threadIdx.x;
    if (b < HD) {
        int h = b >> 6, d = b & 63;
        const float* Wh = W + (size_t)h * IN_F * DH + d;
        __bf16* dst = Wt + (size_t)b * IN_F;
        for (int f = lane; f < IN_F; f += 64)
            dst[f] = (__bf16)Wh[f * DH];
    } else {
        int h = b - HD;
        const float* Wh = W + (size_t)h * IN_F * DH;
        const float* ah = a_dst + h * DH;
        for (int f = lane; f < IN_F; f += 64) {
            const float* row = Wh + (size_t)f * DH;
            float s = 0.f;
            #pragma unroll 8
            for (int d = 0; d < DH; ++d) s += row[d] * ah[d];
            v[h * IN_F + f] = s;
        }
    }
}

// ---------------- Kernel 1: GEMM  mx[n][c] = sum_f x[n][f] * Wt[c][f]
// fp32 X converted to bf16 during LDS staging; bf16 MFMA, fp32 acc, bf16 out.
#define BM 128
#define BN 64
#define BK 32
#define KP (BK + 8)   // padded LDS k-stride: 40 bf16 = 80 B (16B-aligned sub-rows)

__global__ __launch_bounds__(256) void k1_gemm(const float* __restrict__ X,
                                               const __bf16* __restrict__ Bt,
                                               __bf16* __restrict__ C) {
    __shared__ __bf16 As[BM][KP];
    __shared__ __bf16 Bs[BN][KP];
    int tid  = threadIdx.x;
    int row0 = blockIdx.x * BM;
    int col0 = blockIdx.y * BN;
    int wave = tid >> 6, lane = tid & 63;
    int wm = wave >> 1, wn = wave & 1;   // wave tile: rows wm*64.., cols wn*32..
    int lr = lane & 15;                  // row/col within 16-tile
    int kg = lane >> 4;                  // k-group 0..3 -> k = kg*8..kg*8+7

    f32x4 acc[4][2] = {};

    // staging maps: A: 16 fp32->bf16 per thread; B: 8 bf16 per thread
    int ar = tid >> 1, ah = (tid & 1) * 16;
    int bc = tid >> 2, bq = (tid & 3) * 8;

    for (int k0 = 0; k0 < IN_F; k0 += BK) {
        const float* asrc = X + (size_t)(row0 + ar) * IN_F + k0 + ah;
        f32x4 f0 = *(const f32x4*)(asrc);
        f32x4 f1 = *(const f32x4*)(asrc + 4);
        f32x4 f2 = *(const f32x4*)(asrc + 8);
        f32x4 f3 = *(const f32x4*)(asrc + 12);
        bf16x8 lo = { (__bf16)f0[0], (__bf16)f0[1], (__bf16)f0[2], (__bf16)f0[3],
                      (__bf16)f1[0], (__bf16)f1[1], (__bf16)f1[2], (__bf16)f1[3] };
        bf16x8 hi = { (__bf16)f2[0], (__bf16)f2[1], (__bf16)f2[2], (__bf16)f2[3],
                      (__bf16)f3[0], (__bf16)f3[1], (__bf16)f3[2], (__bf16)f3[3] };
        *(bf16x8*)&As[ar][ah]     = lo;
        *(bf16x8*)&As[ar][ah + 8] = hi;
        *(uint4*)&Bs[bc][bq] = *(const uint4*)(Bt + (size_t)(col0 + bc) * IN_F + k0 + bq);
        __syncthreads();

        bf16x8 af[4], bfv[2];
        #pragma unroll
        for (int mt = 0; mt < 4; ++mt)
            af[mt] = *(const bf16x8*)&As[wm * 64 + mt * 16 + lr][kg * 8];
        #pragma unroll
        for (int nt = 0; nt < 2; ++nt)
            bfv[nt] = *(const bf16x8*)&Bs[wn * 32 + nt * 16 + lr][kg * 8];
        #pragma unroll
        for (int mt = 0; mt < 4; ++mt)
            #pragma unroll
            for (int nt = 0; nt < 2; ++nt)
                acc[mt][nt] = __builtin_amdgcn_mfma_f32_16x16x32_bf16(af[mt], bfv[nt], acc[mt][nt], 0, 0, 0);
        __syncthreads();
    }

    // epilogue: C/D layout col=lane&15, row=(lane>>4)*4+reg
    #pragma unroll
    for (int mt = 0; mt < 4; ++mt) {
        #pragma unroll
        for (int nt = 0; nt < 2; ++nt) {
            int col = col0 + wn * 32 + nt * 16 + lr;
            #pragma unroll
            for (int r = 0; r < 4; ++r) {
                int row = row0 + wm * 64 + mt * 16 + kg * 4 + r;
                C[(size_t)row * HD + col] = (__bf16)acc[mt][nt][r];
            }
        }
    }
}

// ---------------- Kernel 2: et[n][h] = exp( sum_f x[n][f] * v[h][f] )  (all fp32, exact logits)
__global__ __launch_bounds__(256) void k2_et(const float* __restrict__ X,
                                             const float* __restrict__ v,
                                             float* __restrict__ et) {
    __shared__ float vs[HEADS * IN_F];   // 16 KB
    int tid = threadIdx.x;
    for (int i = tid; i < HEADS * IN_F; i += 256) vs[i] = v[i];
    __syncthreads();
    int g = blockIdx.x * 256 + tid;
    int n = g >> 3, h = g & 7;
    const float* xr = X + (size_t)n * IN_F;
    const float* vh = vs + h * IN_F;
    float s = 0.f;
    for (int f = 0; f < IN_F; f += 4) {
        f32x4 xv = *(const f32x4*)&xr[f];
        s += xv[0] * vh[f] + xv[1] * vh[f + 1] + xv[2] * vh[f + 2] + xv[3] * vh[f + 3];
    }
    et[g] = __expf(s);
}

// ---------------- Kernel 3: per row i — neighbor scan + softmax-weighted aggregation
#define MAXNBR 512
__global__ __launch_bounds__(256) void k3_aggr(const float* __restrict__ adj,
                                               const __bf16* __restrict__ mx,
                                               const float* __restrict__ et,
                                               float* __restrict__ out) {
    __shared__ int   jlist[MAXNBR];
    __shared__ float el[MAXNBR * 8];   // 16 KB
    __shared__ int   cnt;
    int tid = threadIdx.x;
    int i   = blockIdx.x;
    if (tid == 0) cnt = 0;
    __syncthreads();

    // phase A: scan adj row (4096 fp32 = 16 KB), 16 entries/thread, push nonzero j
    {
        const float* arow = adj + (size_t)i * N_NODES;
        int j0 = tid * 16;
        #pragma unroll
        for (int q = 0; q < 4; ++q) {
            uint4 p = *(const uint4*)(arow + j0 + q * 4);
            int jb = j0 + q * 4;
            if (p.x) { int s = atomicAdd(&cnt, 1); jlist[s] = jb;     }
            if (p.y) { int s = atomicAdd(&cnt, 1); jlist[s] = jb + 1; }
            if (p.z) { int s = atomicAdd(&cnt, 1); jlist[s] = jb + 2; }
            if (p.w) { int s = atomicAdd(&cnt, 1); jlist[s] = jb + 3; }
        }
    }
    __syncthreads();
    int c = cnt;

    // phase A2: gather exp(t) for neighbors, all heads (et[j][h] contiguous)
    for (int idx = tid; idx < c * 8; idx += 256)
        el[idx] = et[(size_t)jlist[idx >> 3] * 8 + (idx & 7)];
    __syncthreads();

    // phase B: thread owns cols c0=tid (head h0), c1=tid+256 (head h0+4)
    int h0 = tid >> 6;
    int c0 = tid, c1 = tid + 256;
    int h1 = h0 + 4;
    float a0 = 0.f, a1 = 0.f, d0 = 0.f, d1 = 0.f;
    for (int k = 0; k < c; ++k) {
        int j = jlist[k];                       // LDS broadcast
        float e0 = el[k * 8 + h0];
        float e1 = el[k * 8 + h1];
        const __bf16* mrow = mx + (size_t)j * HD;
        a0 += e0 * (float)mrow[c0];
        a1 += e1 * (float)mrow[c1];
        d0 += e0; d1 += e1;
    }
    out[(size_t)i * HD + c0] = a0 / d0;
    out[(size_t)i * HD + c1] = a1 / d1;
}

extern "C" void kernel_launch(void* const* d_in, const int* in_sizes, int n_in,
                              void* d_out, int out_size, void* d_ws, size_t ws_size,
                              hipStream_t stream) {
    const float* x     = (const float*)d_in[0];
    const float* adj   = (const float*)d_in[1];
    const float* W     = (const float*)d_in[2];
    // d_in[3] = a_origin: mathematically dead (softmax shift invariance over j)
    const float* a_dst = (const float*)d_in[4];
    float* out = (float*)d_out;

    char* ws = (char*)d_ws;
    __bf16* Wt = (__bf16*)ws;                     // 512 KB  [512][512]
    float*  v  = (float*)(ws + 524288);           // 16 KB   [8][512]
    __bf16* mx = (__bf16*)(ws + 540672);          // 4 MB    [4096][512]
    float*  et = (float*)(ws + 4734976);          // 128 KB  [4096][8]

    k0_prep<<<dim3(HD + HEADS), dim3(64), 0, stream>>>(W, a_dst, Wt, v);
    k1_gemm<<<dim3(N_NODES / BM, HD / BN), dim3(256), 0, stream>>>(x, Wt, mx);
    k2_et  <<<dim3(N_NODES * HEADS / 256), dim3(256), 0, stream>>>(x, v, et);
    k3_aggr<<<dim3(N_NODES), dim3(256), 0, stream>>>(adj, mx, et, out);
}

// Round 3
// 152.398 us; speedup vs baseline: 1.0743x; 1.0743x over previous
//
#include <hip/hip_runtime.h>
#include <hip/hip_bf16.h>

#define N_NODES 4096
#define IN_F    512
#define HEADS   8
#define DH      64
#define HD      512   // HEADS*DH

typedef __bf16 bf16x8 __attribute__((ext_vector_type(8)));
typedef float  f32x4  __attribute__((ext_vector_type(4)));

__device__ __forceinline__ float bf_lo(unsigned u) { return __uint_as_float(u << 16); }
__device__ __forceinline__ float bf_hi(unsigned u) { return __uint_as_float(u & 0xffff0000u); }

// ---------------- Kernel 0: prep
// blocks 0..63 : coalesced LDS-tiled transpose  Wt[h*64+d][f] = bf16(W[h][f][d])
// blocks 64..71: vt[f*8+h] = sum_d W[h][f][d] * a_dst[h][d]   (fp32, transposed for k2)
__global__ __launch_bounds__(256) void k0_prep(const float* __restrict__ W,
                                               const float* __restrict__ a_dst,
                                               __bf16* __restrict__ Wt,
                                               float* __restrict__ vt) {
    __shared__ __bf16 T[64][72];   // 9216 B, rows 144 B (16B-aligned)
    __shared__ float ad[64];
    int b = blockIdx.x, tid = threadIdx.x;
    if (b < 64) {
        int h = b >> 3, f0 = (b & 7) * 64;
        int fl = tid >> 2, dq = (tid & 3) * 16;
        const float* src = W + ((size_t)h * IN_F + f0 + fl) * DH + dq;
        f32x4 r0 = *(const f32x4*)src, r1 = *(const f32x4*)(src + 4);
        f32x4 r2 = *(const f32x4*)(src + 8), r3 = *(const f32x4*)(src + 12);
        __bf16* t = &T[fl][dq];
        t[0]=(__bf16)r0[0]; t[1]=(__bf16)r0[1]; t[2]=(__bf16)r0[2]; t[3]=(__bf16)r0[3];
        t[4]=(__bf16)r1[0]; t[5]=(__bf16)r1[1]; t[6]=(__bf16)r1[2]; t[7]=(__bf16)r1[3];
        t[8]=(__bf16)r2[0]; t[9]=(__bf16)r2[1]; t[10]=(__bf16)r2[2]; t[11]=(__bf16)r2[3];
        t[12]=(__bf16)r3[0]; t[13]=(__bf16)r3[1]; t[14]=(__bf16)r3[2]; t[15]=(__bf16)r3[3];
        __syncthreads();
        int d = tid >> 2, fq = (tid & 3) * 16;
        __bf16 tmp[16];
        #pragma unroll
        for (int q = 0; q < 16; ++q) tmp[q] = T[fq + q][d];
        __bf16* dst = Wt + ((size_t)h * 64 + d) * IN_F + f0 + fq;
        *(bf16x8*)dst       = *(bf16x8*)&tmp[0];
        *(bf16x8*)(dst + 8) = *(bf16x8*)&tmp[8];
    } else {
        int h = b - 64;
        if (tid < 64) ad[tid] = a_dst[h * DH + tid];
        __syncthreads();
        for (int f = tid; f < IN_F; f += 256) {
            const float* row = W + ((size_t)h * IN_F + f) * DH;
            float s = 0.f;
            #pragma unroll
            for (int d4 = 0; d4 < DH; d4 += 4) {
                f32x4 r = *(const f32x4*)(row + d4);
                s += r[0]*ad[d4] + r[1]*ad[d4+1] + r[2]*ad[d4+2] + r[3]*ad[d4+3];
            }
            vt[f * HEADS + h] = s;
        }
    }
}

// ---------------- Kernel 1: GEMM  mx[n][c] = sum_f x[n][f] * Wt[c][f]
// fp32 X -> bf16 during staging; register-prefetch + double-buffered LDS (1 barrier/iter).
#define BM 128
#define BN 64
#define BK 32
#define KP (BK + 8)   // 40 bf16 = 80 B rows (16B-aligned sub-rows)

__global__ __launch_bounds__(256) void k1_gemm(const float* __restrict__ X,
                                               const __bf16* __restrict__ Bt,
                                               __bf16* __restrict__ C) {
    __shared__ __bf16 As[2][BM][KP];
    __shared__ __bf16 Bs[2][BN][KP];
    int tid  = threadIdx.x;
    // grid: x = col-block (8), y = row-block (32) -> consecutive block ids span col-blocks
    // -> XCD round-robin pins one 64KB B-slab per XCD L2.
    int row0 = blockIdx.y * BM;
    int col0 = blockIdx.x * BN;
    int wave = tid >> 6, lane = tid & 63;
    int wm = wave >> 1, wn = wave & 1;
    int lr = lane & 15;
    int kg = lane >> 4;

    f32x4 acc[4][2] = {};

    int ar = tid >> 1, ah = (tid & 1) * 16;   // A staging: 16 fp32/thread
    int bc = tid >> 2, bq = (tid & 3) * 8;    // B staging: 8 bf16/thread

    const float* aptr = X + (size_t)(row0 + ar) * IN_F + ah;
    const __bf16* bptr = Bt + (size_t)(col0 + bc) * IN_F + bq;

    f32x4 ga0, ga1, ga2, ga3; uint4 gb;
    // prologue: load tile 0
    ga0 = *(const f32x4*)(aptr);      ga1 = *(const f32x4*)(aptr + 4);
    ga2 = *(const f32x4*)(aptr + 8);  ga3 = *(const f32x4*)(aptr + 12);
    gb  = *(const uint4*)(bptr);

    for (int k = 0; k < IN_F / BK; ++k) {
        int cur = k & 1;
        bf16x8 lo = { (__bf16)ga0[0], (__bf16)ga0[1], (__bf16)ga0[2], (__bf16)ga0[3],
                      (__bf16)ga1[0], (__bf16)ga1[1], (__bf16)ga1[2], (__bf16)ga1[3] };
        bf16x8 hi = { (__bf16)ga2[0], (__bf16)ga2[1], (__bf16)ga2[2], (__bf16)ga2[3],
                      (__bf16)ga3[0], (__bf16)ga3[1], (__bf16)ga3[2], (__bf16)ga3[3] };
        *(bf16x8*)&As[cur][ar][ah]     = lo;
        *(bf16x8*)&As[cur][ar][ah + 8] = hi;
        *(uint4*)&Bs[cur][bc][bq]      = gb;
        if (k + 1 < IN_F / BK) {
            const float* ap = aptr + (k + 1) * BK;
            ga0 = *(const f32x4*)(ap);      ga1 = *(const f32x4*)(ap + 4);
            ga2 = *(const f32x4*)(ap + 8);  ga3 = *(const f32x4*)(ap + 12);
            gb  = *(const uint4*)(bptr + (k + 1) * BK);
        }
        __syncthreads();
        bf16x8 af[4], bfv[2];
        #pragma unroll
        for (int mt = 0; mt < 4; ++mt)
            af[mt] = *(const bf16x8*)&As[cur][wm * 64 + mt * 16 + lr][kg * 8];
        #pragma unroll
        for (int nt = 0; nt < 2; ++nt)
            bfv[nt] = *(const bf16x8*)&Bs[cur][wn * 32 + nt * 16 + lr][kg * 8];
        #pragma unroll
        for (int mt = 0; mt < 4; ++mt)
            #pragma unroll
            for (int nt = 0; nt < 2; ++nt)
                acc[mt][nt] = __builtin_amdgcn_mfma_f32_16x16x32_bf16(af[mt], bfv[nt], acc[mt][nt], 0, 0, 0);
        // no second barrier: next iter writes the OTHER buffer; its previous readers
        // are separated by this iter's barrier + lgkmcnt drain.
    }

    // epilogue: C/D layout col=lane&15, row=(lane>>4)*4+reg
    #pragma unroll
    for (int mt = 0; mt < 4; ++mt) {
        #pragma unroll
        for (int nt = 0; nt < 2; ++nt) {
            int col = col0 + wn * 32 + nt * 16 + lr;
            #pragma unroll
            for (int r = 0; r < 4; ++r) {
                int row = row0 + wm * 64 + mt * 16 + kg * 4 + r;
                C[(size_t)row * HD + col] = (__bf16)acc[mt][nt][r];
            }
        }
    }
}

// ---------------- Kernel 2: et[n][h] = exp( sum_f x[n][f] * vt[f][h] )  (fp32, exact logits)
__global__ __launch_bounds__(256) void k2_et(const float* __restrict__ X,
                                             const float* __restrict__ vt,
                                             float* __restrict__ et) {
    __shared__ float vs[IN_F * HEADS];   // [f][h] layout: head-lanes hit consecutive banks
    int tid = threadIdx.x;
    for (int i = tid; i < IN_F * HEADS; i += 256) vs[i] = vt[i];
    __syncthreads();
    int g = blockIdx.x * 256 + tid;
    int n = g >> 3, h = g & 7;
    const float* xr = X + (size_t)n * IN_F;
    float s = 0.f;
    for (int f = 0; f < IN_F; f += 4) {
        f32x4 xv = *(const f32x4*)&xr[f];
        s += xv[0] * vs[(f    ) * 8 + h] + xv[1] * vs[(f + 1) * 8 + h]
           + xv[2] * vs[(f + 2) * 8 + h] + xv[3] * vs[(f + 3) * 8 + h];
    }
    et[g] = __expf(s);
}

// ---------------- Kernel 3: per row i — neighbor scan + softmax-weighted aggregation
#define MAXNBR 512
__global__ __launch_bounds__(256) void k3_aggr(const float* __restrict__ adj,
                                               const __bf16* __restrict__ mx,
                                               const float* __restrict__ et,
                                               float* __restrict__ out) {
    __shared__ int   jlist[MAXNBR];
    __shared__ float el[MAXNBR * 8];
    __shared__ int   cnt;
    int tid = threadIdx.x;
    int i   = blockIdx.x;
    if (tid == 0) cnt = 0;
    __syncthreads();

    // phase A: scan adj row (16 KB), push nonzero j
    {
        const float* arow = adj + (size_t)i * N_NODES;
        int j0 = tid * 16;
        #pragma unroll
        for (int q = 0; q < 4; ++q) {
            uint4 p = *(const uint4*)(arow + j0 + q * 4);
            int jb = j0 + q * 4;
            if (p.x) { int s = atomicAdd(&cnt, 1); if (s < MAXNBR) jlist[s] = jb;     }
            if (p.y) { int s = atomicAdd(&cnt, 1); if (s < MAXNBR) jlist[s] = jb + 1; }
            if (p.z) { int s = atomicAdd(&cnt, 1); if (s < MAXNBR) jlist[s] = jb + 2; }
            if (p.w) { int s = atomicAdd(&cnt, 1); if (s < MAXNBR) jlist[s] = jb + 3; }
        }
    }
    __syncthreads();
    int c = cnt < MAXNBR ? cnt : MAXNBR;

    // phase A2: gather exp(t) for neighbors, all heads
    for (int idx = tid; idx < c * 8; idx += 256)
        el[idx] = et[(size_t)jlist[idx >> 3] * 8 + (idx & 7)];
    __syncthreads();

    // phase B: thread owns 2 adjacent cols (2tid, 2tid+1) of head h = tid>>5; one 4B load per j.
    int h = tid >> 5;
    const unsigned* mxu = (const unsigned*)mx;   // 256 uints per row
    float a0 = 0.f, a1 = 0.f, d = 0.f;
    int k = 0;
    for (; k + 4 <= c; k += 4) {
        int j0_ = jlist[k], j1_ = jlist[k+1], j2_ = jlist[k+2], j3_ = jlist[k+3];
        float e0 = el[(k    ) * 8 + h], e1 = el[(k + 1) * 8 + h];
        float e2 = el[(k + 2) * 8 + h], e3 = el[(k + 3) * 8 + h];
        unsigned p0 = mxu[(size_t)j0_ * 256 + tid];
        unsigned p1 = mxu[(size_t)j1_ * 256 + tid];
        unsigned p2 = mxu[(size_t)j2_ * 256 + tid];
        unsigned p3 = mxu[(size_t)j3_ * 256 + tid];
        a0 += e0 * bf_lo(p0) + e1 * bf_lo(p1) + e2 * bf_lo(p2) + e3 * bf_lo(p3);
        a1 += e0 * bf_hi(p0) + e1 * bf_hi(p1) + e2 * bf_hi(p2) + e3 * bf_hi(p3);
        d  += e0 + e1 + e2 + e3;
    }
    for (; k < c; ++k) {
        int j = jlist[k];
        float e = el[k * 8 + h];
        unsigned p = mxu[(size_t)j * 256 + tid];
        a0 += e * bf_lo(p);
        a1 += e * bf_hi(p);
        d  += e;
    }
    float inv = 1.f / d;
    out[(size_t)i * HD + tid * 2]     = a0 * inv;
    out[(size_t)i * HD + tid * 2 + 1] = a1 * inv;
}

extern "C" void kernel_launch(void* const* d_in, const int* in_sizes, int n_in,
                              void* d_out, int out_size, void* d_ws, size_t ws_size,
                              hipStream_t stream) {
    const float* x     = (const float*)d_in[0];
    const float* adj   = (const float*)d_in[1];
    const float* W     = (const float*)d_in[2];
    // d_in[3] = a_origin: dead (softmax shift invariance over j)
    const float* a_dst = (const float*)d_in[4];
    float* out = (float*)d_out;

    char* ws = (char*)d_ws;
    __bf16* Wt = (__bf16*)ws;                     // 512 KB  [512][512]
    float*  vt = (float*)(ws + 524288);           // 16 KB   [512][8]
    __bf16* mx = (__bf16*)(ws + 540672);          // 4 MB    [4096][512]
    float*  et = (float*)(ws + 4734976);          // 128 KB  [4096][8]

    k0_prep<<<dim3(64 + HEADS), dim3(256), 0, stream>>>(W, a_dst, Wt, vt);
    k2_et  <<<dim3(N_NODES * HEADS / 256), dim3(256), 0, stream>>>(x, vt, et);
    k1_gemm<<<dim3(HD / BN, N_NODES / BM), dim3(256), 0, stream>>>(x, Wt, mx);
    k3_aggr<<<dim3(N_NODES), dim3(256), 0, stream>>>(adj, mx, et, out);
}

// Round 4
// 144.292 us; speedup vs baseline: 1.1346x; 1.0562x over previous
//
#include <hip/hip_runtime.h>
#include <hip/hip_bf16.h>

#define N_NODES 4096
#define IN_F    512
#define HEADS   8
#define DH      64
#define HD      512   // HEADS*DH

typedef __bf16 bf16x8 __attribute__((ext_vector_type(8)));
typedef float  f32x4  __attribute__((ext_vector_type(4)));

__device__ __forceinline__ float bf_lo(unsigned u) { return __uint_as_float(u << 16); }
__device__ __forceinline__ float bf_hi(unsigned u) { return __uint_as_float(u & 0xffff0000u); }

// ---------------- Kernel 0: prep
// blocks 0..63  : LDS-tiled transpose  Wt[h*64+d][f] = bf16(W[h][f][d])
// blocks 64..71 : vt[f*8+h] = sum_d W[h][f][d] * a_dst[h][d]   (fp32, exact logits)
// blocks 72..199: Xb = bf16(X)   (A-operand pre-conversion for k1)
__global__ __launch_bounds__(256) void k0_prep(const float* __restrict__ X,
                                               const float* __restrict__ W,
                                               const float* __restrict__ a_dst,
                                               __bf16* __restrict__ Xb,
                                               __bf16* __restrict__ Wt,
                                               float* __restrict__ vt) {
    __shared__ __bf16 T[64][72];
    __shared__ float ad[64];
    int b = blockIdx.x, tid = threadIdx.x;
    if (b < 64) {
        int h = b >> 3, f0 = (b & 7) * 64;
        int fl = tid >> 2, dq = (tid & 3) * 16;
        const float* src = W + ((size_t)h * IN_F + f0 + fl) * DH + dq;
        f32x4 r0 = *(const f32x4*)src, r1 = *(const f32x4*)(src + 4);
        f32x4 r2 = *(const f32x4*)(src + 8), r3 = *(const f32x4*)(src + 12);
        __bf16* t = &T[fl][dq];
        t[0]=(__bf16)r0[0]; t[1]=(__bf16)r0[1]; t[2]=(__bf16)r0[2]; t[3]=(__bf16)r0[3];
        t[4]=(__bf16)r1[0]; t[5]=(__bf16)r1[1]; t[6]=(__bf16)r1[2]; t[7]=(__bf16)r1[3];
        t[8]=(__bf16)r2[0]; t[9]=(__bf16)r2[1]; t[10]=(__bf16)r2[2]; t[11]=(__bf16)r2[3];
        t[12]=(__bf16)r3[0]; t[13]=(__bf16)r3[1]; t[14]=(__bf16)r3[2]; t[15]=(__bf16)r3[3];
        __syncthreads();
        int d = tid >> 2, fq = (tid & 3) * 16;
        __bf16 tmp[16];
        #pragma unroll
        for (int q = 0; q < 16; ++q) tmp[q] = T[fq + q][d];
        __bf16* dst = Wt + ((size_t)h * 64 + d) * IN_F + f0 + fq;
        *(bf16x8*)dst       = *(bf16x8*)&tmp[0];
        *(bf16x8*)(dst + 8) = *(bf16x8*)&tmp[8];
    } else if (b < 72) {
        int h = b - 64;
        if (tid < 64) ad[tid] = a_dst[h * DH + tid];
        __syncthreads();
        for (int f = tid; f < IN_F; f += 256) {
            const float* row = W + ((size_t)h * IN_F + f) * DH;
            float s = 0.f;
            #pragma unroll
            for (int d4 = 0; d4 < DH; d4 += 4) {
                f32x4 r = *(const f32x4*)(row + d4);
                s += r[0]*ad[d4] + r[1]*ad[d4+1] + r[2]*ad[d4+2] + r[3]*ad[d4+3];
            }
            vt[f * HEADS + h] = s;
        }
    } else {
        int gid = (b - 72) * 256 + tid;
        const int NCH = N_NODES * IN_F / 8;
        for (int c = gid; c < NCH; c += 128 * 256) {
            const float* src = X + (size_t)c * 8;
            f32x4 r0 = *(const f32x4*)src, r1 = *(const f32x4*)(src + 4);
            bf16x8 o = { (__bf16)r0[0], (__bf16)r0[1], (__bf16)r0[2], (__bf16)r0[3],
                         (__bf16)r1[0], (__bf16)r1[1], (__bf16)r1[2], (__bf16)r1[3] };
            *(bf16x8*)(Xb + (size_t)c * 8) = o;
        }
    }
}

// ---------------- Kernel 1: GEMM  mx[n][c] = sum_f Xb[n][f] * Wt[c][f]
// BM=BN=BK=64, 512 blocks (2/CU, 2 waves/SIMD), register-prefetch + dbuf LDS, 1 barrier/iter.
#define BM 64
#define BN 64
#define BK 64
#define KP 72   // 144 B rows: 16B-aligned, <=2-way bank aliasing per 16-lane phase

__global__ __launch_bounds__(256) void k1_gemm(const __bf16* __restrict__ Xb,
                                               const __bf16* __restrict__ Bt,
                                               __bf16* __restrict__ C) {
    __shared__ __bf16 As[2][BM][KP];
    __shared__ __bf16 Bs[2][BN][KP];
    int tid  = threadIdx.x;
    int row0 = blockIdx.y * BM;
    int col0 = blockIdx.x * BN;   // gridDim.x=8 -> col-blocks round-robin the 8 XCDs
    int wave = tid >> 6, lane = tid & 63;
    int wm = wave >> 1, wn = wave & 1;
    int lr = lane & 15, kg = lane >> 4;

    f32x4 acc[2][2] = {};

    int sr = tid >> 3;          // staging row 0..31
    int sc = (tid & 7) * 8;     // staging elem offset
    const __bf16* aptr0 = Xb + (size_t)(row0 + sr) * IN_F + sc;
    const __bf16* aptr1 = aptr0 + (size_t)32 * IN_F;
    const __bf16* bptr0 = Bt + (size_t)(col0 + sr) * IN_F + sc;
    const __bf16* bptr1 = bptr0 + (size_t)32 * IN_F;

    uint4 pa0 = *(const uint4*)aptr0, pa1 = *(const uint4*)aptr1;
    uint4 pb0 = *(const uint4*)bptr0, pb1 = *(const uint4*)bptr1;

    #pragma unroll
    for (int k = 0; k < IN_F / BK; ++k) {
        int cur = k & 1;
        *(uint4*)&As[cur][sr][sc]      = pa0;
        *(uint4*)&As[cur][sr + 32][sc] = pa1;
        *(uint4*)&Bs[cur][sr][sc]      = pb0;
        *(uint4*)&Bs[cur][sr + 32][sc] = pb1;
        if (k + 1 < IN_F / BK) {
            int off = (k + 1) * BK;
            pa0 = *(const uint4*)(aptr0 + off);
            pa1 = *(const uint4*)(aptr1 + off);
            pb0 = *(const uint4*)(bptr0 + off);
            pb1 = *(const uint4*)(bptr1 + off);
        }
        __syncthreads();
        #pragma unroll
        for (int kc = 0; kc < 2; ++kc) {
            bf16x8 af0 = *(const bf16x8*)&As[cur][wm * 32 + lr]     [kc * 32 + kg * 8];
            bf16x8 af1 = *(const bf16x8*)&As[cur][wm * 32 + 16 + lr][kc * 32 + kg * 8];
            bf16x8 bf0 = *(const bf16x8*)&Bs[cur][wn * 32 + lr]     [kc * 32 + kg * 8];
            bf16x8 bf1 = *(const bf16x8*)&Bs[cur][wn * 32 + 16 + lr][kc * 32 + kg * 8];
            acc[0][0] = __builtin_amdgcn_mfma_f32_16x16x32_bf16(af0, bf0, acc[0][0], 0, 0, 0);
            acc[0][1] = __builtin_amdgcn_mfma_f32_16x16x32_bf16(af0, bf1, acc[0][1], 0, 0, 0);
            acc[1][0] = __builtin_amdgcn_mfma_f32_16x16x32_bf16(af1, bf0, acc[1][0], 0, 0, 0);
            acc[1][1] = __builtin_amdgcn_mfma_f32_16x16x32_bf16(af1, bf1, acc[1][1], 0, 0, 0);
        }
        // single barrier/iter is safe: DS pipe is in-order per wave; the buffer
        // written at iter k+1 was last read at k-1, separated by barrier k.
    }

    // epilogue: C/D layout col=lane&15, row=(lane>>4)*4+reg
    #pragma unroll
    for (int mt = 0; mt < 2; ++mt) {
        #pragma unroll
        for (int nt = 0; nt < 2; ++nt) {
            int col = col0 + wn * 32 + nt * 16 + lr;
            #pragma unroll
            for (int r = 0; r < 4; ++r) {
                int row = row0 + wm * 32 + mt * 16 + kg * 4 + r;
                C[(size_t)row * HD + col] = (__bf16)acc[mt][nt][r];
            }
        }
    }
}

// ---------------- Kernel 2: et[n][h] = exp( sum_f x[n][f] * vt[f][h] )  (fp32, exact)
__global__ __launch_bounds__(256) void k2_et(const float* __restrict__ X,
                                             const float* __restrict__ vt,
                                             float* __restrict__ et) {
    __shared__ float vs[IN_F * HEADS];   // [f][h]: head-lanes hit consecutive banks
    int tid = threadIdx.x;
    for (int i = tid; i < IN_F * HEADS; i += 256) vs[i] = vt[i];
    __syncthreads();
    int g = blockIdx.x * 256 + tid;
    int n = g >> 3, h = g & 7;
    const float* xr = X + (size_t)n * IN_F;
    float s = 0.f;
    for (int f = 0; f < IN_F; f += 4) {
        f32x4 xv = *(const f32x4*)&xr[f];
        s += xv[0] * vs[(f    ) * 8 + h] + xv[1] * vs[(f + 1) * 8 + h]
           + xv[2] * vs[(f + 2) * 8 + h] + xv[3] * vs[(f + 3) * 8 + h];
    }
    et[g] = __expf(s);
}

// ---------------- Kernel 3: per row i — neighbor scan + softmax-weighted aggregation
#define MAXNBR 512
__global__ __launch_bounds__(256) void k3_aggr(const float* __restrict__ adj,
                                               const __bf16* __restrict__ mx,
                                               const float* __restrict__ et,
                                               float* __restrict__ out) {
    __shared__ int   jlist[MAXNBR];
    __shared__ float el[MAXNBR * 8];
    __shared__ int   cnt;
    int tid = threadIdx.x;
    int i   = blockIdx.x;
    if (tid == 0) cnt = 0;
    __syncthreads();

    // phase A: scan adj row (16 KB coalesced), push nonzero j
    {
        const float* arow = adj + (size_t)i * N_NODES;
        int j0 = tid * 16;
        #pragma unroll
        for (int q = 0; q < 4; ++q) {
            uint4 p = *(const uint4*)(arow + j0 + q * 4);
            int jb = j0 + q * 4;
            if (p.x) { int s = atomicAdd(&cnt, 1); if (s < MAXNBR) jlist[s] = jb;     }
            if (p.y) { int s = atomicAdd(&cnt, 1); if (s < MAXNBR) jlist[s] = jb + 1; }
            if (p.z) { int s = atomicAdd(&cnt, 1); if (s < MAXNBR) jlist[s] = jb + 2; }
            if (p.w) { int s = atomicAdd(&cnt, 1); if (s < MAXNBR) jlist[s] = jb + 3; }
        }
    }
    __syncthreads();
    int c = cnt < MAXNBR ? cnt : MAXNBR;

    // phase A2: gather exp(t) for neighbors, all heads
    for (int idx = tid; idx < c * 8; idx += 256)
        el[idx] = et[(size_t)jlist[idx >> 3] * 8 + (idx & 7)];
    __syncthreads();

    // phase B: thread owns 2 adjacent cols (2tid, 2tid+1), head h = tid>>5; one 4B load/j.
    int h = tid >> 5;
    const unsigned* mxu = (const unsigned*)mx;   // 256 uints per row
    float a0 = 0.f, a1 = 0.f, d = 0.f;
    int k = 0;
    for (; k + 4 <= c; k += 4) {
        int j0_ = jlist[k], j1_ = jlist[k+1], j2_ = jlist[k+2], j3_ = jlist[k+3];
        float e0 = el[(k    ) * 8 + h], e1 = el[(k + 1) * 8 + h];
        float e2 = el[(k + 2) * 8 + h], e3 = el[(k + 3) * 8 + h];
        unsigned p0 = mxu[(size_t)j0_ * 256 + tid];
        unsigned p1 = mxu[(size_t)j1_ * 256 + tid];
        unsigned p2 = mxu[(size_t)j2_ * 256 + tid];
        unsigned p3 = mxu[(size_t)j3_ * 256 + tid];
        a0 += e0 * bf_lo(p0) + e1 * bf_lo(p1) + e2 * bf_lo(p2) + e3 * bf_lo(p3);
        a1 += e0 * bf_hi(p0) + e1 * bf_hi(p1) + e2 * bf_hi(p2) + e3 * bf_hi(p3);
        d  += e0 + e1 + e2 + e3;
    }
    for (; k < c; ++k) {
        int j = jlist[k];
        float e = el[k * 8 + h];
        unsigned p = mxu[(size_t)j * 256 + tid];
        a0 += e * bf_lo(p);
        a1 += e * bf_hi(p);
        d  += e;
    }
    float inv = 1.f / d;
    out[(size_t)i * HD + tid * 2]     = a0 * inv;
    out[(size_t)i * HD + tid * 2 + 1] = a1 * inv;
}

extern "C" void kernel_launch(void* const* d_in, const int* in_sizes, int n_in,
                              void* d_out, int out_size, void* d_ws, size_t ws_size,
                              hipStream_t stream) {
    const float* x     = (const float*)d_in[0];
    const float* adj   = (const float*)d_in[1];
    const float* W     = (const float*)d_in[2];
    // d_in[3] = a_origin: dead (softmax shift invariance over j)
    const float* a_dst = (const float*)d_in[4];
    float* out = (float*)d_out;

    char* ws = (char*)d_ws;
    __bf16* Wt = (__bf16*)ws;                     // 512 KB  [512][512]
    float*  vt = (float*)(ws + 524288);           // 16 KB   [512][8]
    __bf16* mx = (__bf16*)(ws + 540672);          // 4 MB    [4096][512]
    float*  et = (float*)(ws + 4734976);          // 128 KB  [4096][8]
    __bf16* xb = (__bf16*)(ws + 4866048);         // 4 MB    [4096][512]

    k0_prep<<<dim3(200), dim3(256), 0, stream>>>(x, W, a_dst, xb, Wt, vt);
    k2_et  <<<dim3(N_NODES * HEADS / 256), dim3(256), 0, stream>>>(x, vt, et);
    k1_gemm<<<dim3(HD / BN, N_NODES / BM), dim3(256), 0, stream>>>(xb, Wt, mx);
    k3_aggr<<<dim3(N_NODES), dim3(256), 0, stream>>>(adj, mx, et, out);
}

// Round 5
// 134.254 us; speedup vs baseline: 1.2194x; 1.0748x over previous
//
#include <hip/hip_runtime.h>
#include <hip/hip_bf16.h>

#define N_NODES 4096
#define IN_F    512
#define HEADS   8
#define DH      64
#define HD      512   // HEADS*DH

typedef __bf16 bf16x8 __attribute__((ext_vector_type(8)));
typedef float  f32x4  __attribute__((ext_vector_type(4)));

__device__ __forceinline__ float bf_lo(unsigned u) { return __uint_as_float(u << 16); }
__device__ __forceinline__ float bf_hi(unsigned u) { return __uint_as_float(u & 0xffff0000u); }

// ---------------- Kernel 0: prep
// blocks 0..63  : LDS-tiled transpose  Wt[h*64+d][f] = bf16(W[h][f][d])
// blocks 64..191: Xb = bf16(X)   (A-operand pre-conversion for k1)
__global__ __launch_bounds__(256) void k0_prep(const float* __restrict__ X,
                                               const float* __restrict__ W,
                                               __bf16* __restrict__ Xb,
                                               __bf16* __restrict__ Wt) {
    __shared__ __bf16 T[64][72];
    int b = blockIdx.x, tid = threadIdx.x;
    if (b < 64) {
        int h = b >> 3, f0 = (b & 7) * 64;
        int fl = tid >> 2, dq = (tid & 3) * 16;
        const float* src = W + ((size_t)h * IN_F + f0 + fl) * DH + dq;
        f32x4 r0 = *(const f32x4*)src, r1 = *(const f32x4*)(src + 4);
        f32x4 r2 = *(const f32x4*)(src + 8), r3 = *(const f32x4*)(src + 12);
        __bf16* t = &T[fl][dq];
        t[0]=(__bf16)r0[0]; t[1]=(__bf16)r0[1]; t[2]=(__bf16)r0[2]; t[3]=(__bf16)r0[3];
        t[4]=(__bf16)r1[0]; t[5]=(__bf16)r1[1]; t[6]=(__bf16)r1[2]; t[7]=(__bf16)r1[3];
        t[8]=(__bf16)r2[0]; t[9]=(__bf16)r2[1]; t[10]=(__bf16)r2[2]; t[11]=(__bf16)r2[3];
        t[12]=(__bf16)r3[0]; t[13]=(__bf16)r3[1]; t[14]=(__bf16)r3[2]; t[15]=(__bf16)r3[3];
        __syncthreads();
        int d = tid >> 2, fq = (tid & 3) * 16;
        __bf16 tmp[16];
        #pragma unroll
        for (int q = 0; q < 16; ++q) tmp[q] = T[fq + q][d];
        __bf16* dst = Wt + ((size_t)h * 64 + d) * IN_F + f0 + fq;
        *(bf16x8*)dst       = *(bf16x8*)&tmp[0];
        *(bf16x8*)(dst + 8) = *(bf16x8*)&tmp[8];
    } else {
        int gid = (b - 64) * 256 + tid;
        const int NCH = N_NODES * IN_F / 8;
        for (int c = gid; c < NCH; c += 128 * 256) {
            const float* src = X + (size_t)c * 8;
            f32x4 r0 = *(const f32x4*)src, r1 = *(const f32x4*)(src + 4);
            bf16x8 o = { (__bf16)r0[0], (__bf16)r0[1], (__bf16)r0[2], (__bf16)r0[3],
                         (__bf16)r1[0], (__bf16)r1[1], (__bf16)r1[2], (__bf16)r1[3] };
            *(bf16x8*)(Xb + (size_t)c * 8) = o;
        }
    }
}

// ---------------- Kernel 1: GEMM  mx[n][c] = sum_f Xb[n][f] * Wt[c][f]
// + fused et epilogue: et[n][h] = exp( sum_d acc_fp32[n][d] * a_dst[h][d] )
// BM=BN=BK=64, 512 blocks (2/CU), register-prefetch + dbuf LDS, 1 barrier/iter.
#define BM 64
#define BN 64
#define BK 64
#define KP 72   // 144 B rows: 16B-aligned, <=2-way bank aliasing per 16-lane phase

__global__ __launch_bounds__(256, 2) void k1_gemm(const __bf16* __restrict__ Xb,
                                                  const __bf16* __restrict__ Bt,
                                                  const float* __restrict__ a_dst,
                                                  __bf16* __restrict__ C,
                                                  float* __restrict__ et) {
    __shared__ __bf16 As[2][BM][KP];
    __shared__ __bf16 Bs[2][BN][KP];
    __shared__ float ts[2][BM];   // per-wn-half row sums for the et epilogue
    int tid  = threadIdx.x;
    int row0 = blockIdx.y * BM;
    int h    = blockIdx.x;        // col-block == head; round-robins the 8 XCDs
    int col0 = h * BN;
    int wave = tid >> 6, lane = tid & 63;
    int wm = wave >> 1, wn = wave & 1;
    int lr = lane & 15, kg = lane >> 4;

    f32x4 acc[2][2] = {};

    int sr = tid >> 3;          // staging row 0..31
    int sc = (tid & 7) * 8;     // staging elem offset
    const __bf16* aptr0 = Xb + (size_t)(row0 + sr) * IN_F + sc;
    const __bf16* aptr1 = aptr0 + (size_t)32 * IN_F;
    const __bf16* bptr0 = Bt + (size_t)(col0 + sr) * IN_F + sc;
    const __bf16* bptr1 = bptr0 + (size_t)32 * IN_F;

    uint4 pa0 = *(const uint4*)aptr0, pa1 = *(const uint4*)aptr1;
    uint4 pb0 = *(const uint4*)bptr0, pb1 = *(const uint4*)bptr1;

    // a_dst values for this lane's two columns (fp32, exact)
    float ad0 = a_dst[h * DH + wn * 32 + lr];
    float ad1 = a_dst[h * DH + wn * 32 + 16 + lr];

    #pragma unroll
    for (int k = 0; k < IN_F / BK; ++k) {
        int cur = k & 1;
        *(uint4*)&As[cur][sr][sc]      = pa0;
        *(uint4*)&As[cur][sr + 32][sc] = pa1;
        *(uint4*)&Bs[cur][sr][sc]      = pb0;
        *(uint4*)&Bs[cur][sr + 32][sc] = pb1;
        if (k + 1 < IN_F / BK) {
            int off = (k + 1) * BK;
            pa0 = *(const uint4*)(aptr0 + off);
            pa1 = *(const uint4*)(aptr1 + off);
            pb0 = *(const uint4*)(bptr0 + off);
            pb1 = *(const uint4*)(bptr1 + off);
        }
        __syncthreads();
        #pragma unroll
        for (int kc = 0; kc < 2; ++kc) {
            bf16x8 af0 = *(const bf16x8*)&As[cur][wm * 32 + lr]     [kc * 32 + kg * 8];
            bf16x8 af1 = *(const bf16x8*)&As[cur][wm * 32 + 16 + lr][kc * 32 + kg * 8];
            bf16x8 bf0 = *(const bf16x8*)&Bs[cur][wn * 32 + lr]     [kc * 32 + kg * 8];
            bf16x8 bf1 = *(const bf16x8*)&Bs[cur][wn * 32 + 16 + lr][kc * 32 + kg * 8];
            acc[0][0] = __builtin_amdgcn_mfma_f32_16x16x32_bf16(af0, bf0, acc[0][0], 0, 0, 0);
            acc[0][1] = __builtin_amdgcn_mfma_f32_16x16x32_bf16(af0, bf1, acc[0][1], 0, 0, 0);
            acc[1][0] = __builtin_amdgcn_mfma_f32_16x16x32_bf16(af1, bf0, acc[1][0], 0, 0, 0);
            acc[1][1] = __builtin_amdgcn_mfma_f32_16x16x32_bf16(af1, bf1, acc[1][1], 0, 0, 0);
        }
        // single barrier/iter: buffer written at k+1 was last read at k-1 (barrier k between)
    }

    // ---- epilogue 1: mx store.  C/D layout: col=lane&15, row=(lane>>4)*4+reg
    #pragma unroll
    for (int mt = 0; mt < 2; ++mt) {
        #pragma unroll
        for (int nt = 0; nt < 2; ++nt) {
            int col = col0 + wn * 32 + nt * 16 + lr;
            #pragma unroll
            for (int r = 0; r < 4; ++r) {
                int row = row0 + wm * 32 + mt * 16 + kg * 4 + r;
                C[(size_t)row * HD + col] = (__bf16)acc[mt][nt][r];
            }
        }
    }

    // ---- epilogue 2: t[row] = sum over this block's 64 cols of acc*a_dst, then exp.
    #pragma unroll
    for (int mt = 0; mt < 2; ++mt) {
        #pragma unroll
        for (int r = 0; r < 4; ++r) {
            float p = ad0 * acc[mt][0][r] + ad1 * acc[mt][1][r];   // this lane's 2 cols
            // reduce over the 16 lr-lanes (xor of bits 0..3 stays inside kg-group)
            p += __shfl_xor(p, 1);
            p += __shfl_xor(p, 2);
            p += __shfl_xor(p, 4);
            p += __shfl_xor(p, 8);
            if (lr == 0)
                ts[wn][wm * 32 + mt * 16 + kg * 4 + r] = p;   // wn-halves disjoint
        }
    }
    __syncthreads();
    if (tid < BM) {
        float t = ts[0][tid] + ts[1][tid];
        et[(size_t)(row0 + tid) * HEADS + h] = __expf(t);
    }
}

// ---------------- Kernel 3: per row i — neighbor scan + softmax-weighted aggregation
#define MAXNBR 512
__global__ __launch_bounds__(256) void k3_aggr(const float* __restrict__ adj,
                                               const __bf16* __restrict__ mx,
                                               const float* __restrict__ et,
                                               float* __restrict__ out) {
    __shared__ int   jlist[MAXNBR];
    __shared__ float el[MAXNBR * 8];
    __shared__ int   cnt;
    int tid = threadIdx.x;
    int i   = blockIdx.x;
    if (tid == 0) cnt = 0;
    __syncthreads();

    // phase A: scan adj row (16 KB coalesced), push nonzero j
    {
        const float* arow = adj + (size_t)i * N_NODES;
        int j0 = tid * 16;
        #pragma unroll
        for (int q = 0; q < 4; ++q) {
            uint4 p = *(const uint4*)(arow + j0 + q * 4);
            int jb = j0 + q * 4;
            if (p.x) { int s = atomicAdd(&cnt, 1); if (s < MAXNBR) jlist[s] = jb;     }
            if (p.y) { int s = atomicAdd(&cnt, 1); if (s < MAXNBR) jlist[s] = jb + 1; }
            if (p.z) { int s = atomicAdd(&cnt, 1); if (s < MAXNBR) jlist[s] = jb + 2; }
            if (p.w) { int s = atomicAdd(&cnt, 1); if (s < MAXNBR) jlist[s] = jb + 3; }
        }
    }
    __syncthreads();
    int c = cnt < MAXNBR ? cnt : MAXNBR;

    // phase A2: gather exp(t) for neighbors, all heads
    for (int idx = tid; idx < c * 8; idx += 256)
        el[idx] = et[(size_t)jlist[idx >> 3] * 8 + (idx & 7)];
    __syncthreads();

    // phase B: thread owns 2 adjacent cols (2tid, 2tid+1), head h = tid>>5; one 4B load/j.
    int h = tid >> 5;
    const unsigned* mxu = (const unsigned*)mx;   // 256 uints per row
    float a0 = 0.f, a1 = 0.f, d = 0.f;
    int k = 0;
    for (; k + 4 <= c; k += 4) {
        int j0_ = jlist[k], j1_ = jlist[k+1], j2_ = jlist[k+2], j3_ = jlist[k+3];
        float e0 = el[(k    ) * 8 + h], e1 = el[(k + 1) * 8 + h];
        float e2 = el[(k + 2) * 8 + h], e3 = el[(k + 3) * 8 + h];
        unsigned p0 = mxu[(size_t)j0_ * 256 + tid];
        unsigned p1 = mxu[(size_t)j1_ * 256 + tid];
        unsigned p2 = mxu[(size_t)j2_ * 256 + tid];
        unsigned p3 = mxu[(size_t)j3_ * 256 + tid];
        a0 += e0 * bf_lo(p0) + e1 * bf_lo(p1) + e2 * bf_lo(p2) + e3 * bf_lo(p3);
        a1 += e0 * bf_hi(p0) + e1 * bf_hi(p1) + e2 * bf_hi(p2) + e3 * bf_hi(p3);
        d  += e0 + e1 + e2 + e3;
    }
    for (; k < c; ++k) {
        int j = jlist[k];
        float e = el[k * 8 + h];
        unsigned p = mxu[(size_t)j * 256 + tid];
        a0 += e * bf_lo(p);
        a1 += e * bf_hi(p);
        d  += e;
    }
    float inv = 1.f / d;
    out[(size_t)i * HD + tid * 2]     = a0 * inv;
    out[(size_t)i * HD + tid * 2 + 1] = a1 * inv;
}

extern "C" void kernel_launch(void* const* d_in, const int* in_sizes, int n_in,
                              void* d_out, int out_size, void* d_ws, size_t ws_size,
                              hipStream_t stream) {
    const float* x     = (const float*)d_in[0];
    const float* adj   = (const float*)d_in[1];
    const float* W     = (const float*)d_in[2];
    // d_in[3] = a_origin: dead (softmax shift invariance over j)
    const float* a_dst = (const float*)d_in[4];
    float* out = (float*)d_out;

    char* ws = (char*)d_ws;
    __bf16* Wt = (__bf16*)ws;                     // 512 KB  [512][512]
    __bf16* mx = (__bf16*)(ws + 524288);          // 4 MB    [4096][512]
    float*  et = (float*)(ws + 4718592);          // 128 KB  [4096][8]
    __bf16* xb = (__bf16*)(ws + 4849664);         // 4 MB    [4096][512]

    k0_prep<<<dim3(192), dim3(256), 0, stream>>>(x, W, xb, Wt);
    k1_gemm<<<dim3(HD / BN, N_NODES / BM), dim3(256), 0, stream>>>(xb, Wt, a_dst, mx, et);
    k3_aggr<<<dim3(N_NODES), dim3(256), 0, stream>>>(adj, mx, et, out);
}